// Round 1
// baseline (140.075 us; speedup 1.0000x reference)
//
#include <hip/hip_runtime.h>

#define B_DIM 4096
#define L_DIM 4096
#define SEGLEN 256
#define NSEG (L_DIM / SEGLEN)   // 16
#define WARM 512                // coupling window for speculative segments (proven exact)
#define CHUNK 64                // time steps per LDS chunk
#define CF4 (CHUNK / 4)         // 16 float4 per row per chunk
#define LSTRIDE 68              // LDS floats per row: 64 + 4 pad (16B-aligned, bank-uniform)

// ws layout: float C_acc[4096], float ts_acc[4096], int first_acc[4096]
__global__ __launch_bounds__(256) void init_kernel(float* wsf, int* wsi) {
    int i = blockIdx.x * 256 + threadIdx.x;
    if (i < 2 * B_DIM) wsf[i] = 0.f;
    if (i < B_DIM) wsi[i] = L_DIM;  // min-identity for first-spike
}

// Exact IEEE step (proven absmax 0): q = RN(u/20) via Markstein, compare off
// the dependent chain: u' = sp_prev ? I' : ((u - q) + I')   [reset == I' exactly]
#define LIF_CORE(IIN)                         \
    float q0 = u * cdiv;                      \
    float rr = fmaf(-20.0f, q0, u);           \
    float q  = fmaf(rr, cdiv, q0);            \
    float a  = u - q;                         \
    float b  = a + (IIN);                     \
    u = sp ? (IIN) : b;                       \
    sp = (u >= 1.0f);

#define WARM_STEP(IIN) { LIF_CORE(IIN) }

#define FULL_STEP(IIN, SOUT)                  \
    {                                         \
        LIF_CORE(IIN)                         \
        float sf = sp ? 1.0f : 0.0f;          \
        cnt += sf;                            \
        seen = fmaxf(seen, sf);               \
        accS += cnt;                          \
        accF += seen;                         \
        (SOUT) = sf;                          \
    }

// Block = 128 threads: wave 0 computes 64 rows (row-per-lane, one time
// segment), wave 1 stages global->LDS (coalesced), double-buffered,
// 1 barrier per chunk. blockIdx: seg = b>>6, rowBase = (b&63)*64.
// NSEG=16 -> grid 1024 = exactly 4 blocks/CU (LDS 4*34816 <= 160K), doubling
// resident waves vs NSEG=8 and cutting the per-block chain 16->12 chunks.
// seg==1 clamps warm start to t=0: exact replay from the true init state.
__global__ __launch_bounds__(128, 1) void lif_kernel(const float* __restrict__ I,
                                                     float* __restrict__ out,
                                                     float* __restrict__ Cacc,
                                                     float* __restrict__ tsAcc,
                                                     int* __restrict__ firstAcc) {
    __shared__ __align__(16) float lds[2][64 * LSTRIDE];
    const int wid = threadIdx.x >> 6;
    const int lane = threadIdx.x & 63;
    const int seg = blockIdx.x >> 6;
    const int rowBase = (blockIdx.x & 63) * 64;
    const int t0 = seg * SEGLEN;
    const int start = (t0 > WARM) ? (t0 - WARM) : 0;
    const int nwarmCh = (t0 - start) / CHUNK;
    const int nch = nwarmCh + SEGLEN / CHUNK;

    if (wid == 1) {
        // ---- producer wave ----
        const int srow = lane >> 4, scol = lane & 15;
        const float* gb = I + (size_t)rowBase * L_DIM + start + scol * 4;
        {
            float* dst = &lds[0][0];
#pragma unroll
            for (int p = 0; p < 16; ++p) {
                const int r = 4 * p + srow;
                float4 v = *(const float4*)(gb + (size_t)r * L_DIM);
                *(float4*)&dst[r * LSTRIDE + scol * 4] = v;
            }
        }
        __syncthreads();
        for (int c = 0; c < nch; ++c) {
            if (c + 1 < nch) {
                const float* g = gb + (c + 1) * CHUNK;
                float* dst = &lds[(c + 1) & 1][0];
#pragma unroll
                for (int p = 0; p < 16; ++p) {
                    const int r = 4 * p + srow;
                    float4 v = *(const float4*)(g + (size_t)r * L_DIM);
                    *(float4*)&dst[r * LSTRIDE + scol * 4] = v;
                }
            }
            __syncthreads();
        }
    } else {
        // ---- compute wave ----
        const int row = rowBase + lane;
        float u = 0.f, cnt = 0.f, seen = 0.f, accS = 0.f, accF = 0.f;
        bool sp = false;
        const float cdiv = 0.05f;  // RN(1/20)
        float* so = out + (size_t)row * L_DIM + t0;

        __syncthreads();  // chunk 0 staged
        for (int c = 0; c < nch; ++c) {
            const float* buf = &lds[c & 1][lane * LSTRIDE];
            float4 R[CF4];
#pragma unroll
            for (int j = 0; j < CF4; ++j) R[j] = *(const float4*)(buf + 4 * j);

            if (c < nwarmCh) {
#pragma unroll
                for (int j = 0; j < CF4; ++j) {
                    float4 iv = R[j];
                    WARM_STEP(iv.x) WARM_STEP(iv.y) WARM_STEP(iv.z) WARM_STEP(iv.w)
                }
            } else {
                float* sd = so + (c - nwarmCh) * CHUNK;
#pragma unroll
                for (int j = 0; j < CF4; ++j) {
                    float4 iv = R[j];
                    float4 sv;
                    FULL_STEP(iv.x, sv.x) FULL_STEP(iv.y, sv.y)
                    FULL_STEP(iv.z, sv.z) FULL_STEP(iv.w, sv.w)
                    *(float4*)(sd + 4 * j) = sv;
                }
            }
            __syncthreads();
        }

        // per-segment partials (all exact integers < 2^24 -> float atomics exact)
        if (cnt > 0.f) {
            const int firstLocal = (int)((float)SEGLEN - accF);
            atomicMin(&firstAcc[row], t0 + firstLocal);
        }
        atomicAdd(&Cacc[row], cnt);
        // sum_t t_global*s = (t0+SEGLEN)*cnt - accS
        atomicAdd(&tsAcc[row], fmaf((float)(t0 + SEGLEN), cnt, -accS));
    }
}

__global__ __launch_bounds__(256) void fin_kernel(const float* __restrict__ Cacc,
                                                  const float* __restrict__ tsAcc,
                                                  const int* __restrict__ firstAcc,
                                                  float* __restrict__ out) {
    int r = blockIdx.x * 256 + threadIdx.x;
    if (r < B_DIM) {
        out[(size_t)B_DIM * L_DIM + r] = (float)firstAcc[r];
        out[(size_t)B_DIM * L_DIM + B_DIM + r] = tsAcc[r] / (Cacc[r] + 1e-6f);
    }
}

extern "C" void kernel_launch(void* const* d_in, const int* in_sizes, int n_in,
                              void* d_out, int out_size, void* d_ws, size_t ws_size,
                              hipStream_t stream) {
    const float* I = (const float*)d_in[0];
    float* out = (float*)d_out;
    float* wsf = (float*)d_ws;
    int* wsi = (int*)((float*)d_ws + 2 * B_DIM);
    (void)in_sizes; (void)n_in; (void)out_size; (void)ws_size;

    init_kernel<<<(2 * B_DIM + 255) / 256, 256, 0, stream>>>(wsf, wsi);
    lif_kernel<<<NSEG * 64, 128, 0, stream>>>(I, out, wsf, wsf + B_DIM, wsi);
    fin_kernel<<<(B_DIM + 255) / 256, 256, 0, stream>>>(wsf, wsf + B_DIM, wsi, out);
}

// Round 2
// 129.885 us; speedup vs baseline: 1.0785x; 1.0785x over previous
//
#include <hip/hip_runtime.h>

#define B_DIM 4096
#define L_DIM 4096
#define SEGLEN 256
#define NSEG (L_DIM / SEGLEN)   // 16
#define WARM 512                // coupling window for speculative segments (proven exact)
#define CHUNK 64                // time steps per LDS chunk
#define CF4 (CHUNK / 4)         // 16 float4 per row per chunk
#define LSTRIDE 68              // LDS floats per row: 64 + 4 pad (16B-aligned, bank-uniform)

// ws layout: float C_acc[4096], float ts_acc[4096], int first_acc[4096]
__global__ __launch_bounds__(256) void init_kernel(float* wsf, int* wsi) {
    int i = blockIdx.x * 256 + threadIdx.x;
    if (i < 2 * B_DIM) wsf[i] = 0.f;
    if (i < B_DIM) wsi[i] = L_DIM;  // min-identity for first-spike
}

// Exact IEEE step (proven absmax 0): q = RN(u/20) via Markstein, compare off
// the dependent chain: u' = sp_prev ? I' : ((u - q) + I')   [reset == I' exactly]
#define LIF_CORE(IIN)                         \
    float q0 = u * cdiv;                      \
    float rr = fmaf(-20.0f, q0, u);           \
    float q  = fmaf(rr, cdiv, q0);            \
    float a  = u - q;                         \
    float b  = a + (IIN);                     \
    u = sp ? (IIN) : b;                       \
    sp = (u >= 1.0f);

#define WARM_STEP(IIN) { LIF_CORE(IIN) }

#define FULL_STEP(IIN, SOUT)                  \
    {                                         \
        LIF_CORE(IIN)                         \
        float sf = sp ? 1.0f : 0.0f;          \
        cnt += sf;                            \
        seen = fmaxf(seen, sf);               \
        accS += cnt;                          \
        accF += seen;                         \
        (SOUT) = sf;                          \
    }

// Block = 128 threads: wave 0 computes 64 rows (row-per-lane, one time
// segment); wave 1 stages global->LDS (coalesced) AND stores spikes
// (coalesced) that wave 0 deposits in LDS. Double-buffered, 1 barrier/chunk.
//
// Phase-c buffer ownership (hazard-free):
//   compute : buf[c&1]      read input-c (burst to regs), write spikes-c
//   producer: buf[(c+1)&1]  read spikes-(c-1) [same buffer], THEN write
//                           input-(c+1) (ds_read precedes aliasing ds_write
//                           in program order -> in-order LDS pipe keeps it safe)
// Compute wave issues ZERO vmem ops: the vmcnt(0)-before-barrier drain that
// serialized 64-line scattered spike stores on the critical path is gone;
// producer's replacement stores are 4-line coalesced.
__global__ __launch_bounds__(128, 1) void lif_kernel(const float* __restrict__ I,
                                                     float* __restrict__ out,
                                                     float* __restrict__ Cacc,
                                                     float* __restrict__ tsAcc,
                                                     int* __restrict__ firstAcc) {
    __shared__ __align__(16) float lds[2][64 * LSTRIDE];
    const int wid = threadIdx.x >> 6;
    const int lane = threadIdx.x & 63;
    const int seg = blockIdx.x >> 6;
    const int rowBase = (blockIdx.x & 63) * 64;
    const int t0 = seg * SEGLEN;
    const int start = (t0 > WARM) ? (t0 - WARM) : 0;
    const int nwarmCh = (t0 - start) / CHUNK;
    const int nch = nwarmCh + SEGLEN / CHUNK;

    if (wid == 1) {
        // ---- producer wave: input staging + coalesced spike stores ----
        const int srow = lane >> 4, scol = lane & 15;
        const float* gb = I + (size_t)rowBase * L_DIM + start + scol * 4;
        float* ob = out + (size_t)rowBase * L_DIM + t0 + scol * 4;
        {
            float* dst = &lds[0][0];
#pragma unroll
            for (int p = 0; p < 16; ++p) {
                const int r = 4 * p + srow;
                float4 v = *(const float4*)(gb + (size_t)r * L_DIM);
                *(float4*)&dst[r * LSTRIDE + scol * 4] = v;
            }
        }
        __syncthreads();
        for (int c = 0; c < nch; ++c) {
            const int cp = c - 1;  // spike chunk deposited last phase
            if (cp >= nwarmCh) {
                float* sb = &lds[cp & 1][0];
                float4 S[16];
#pragma unroll
                for (int p = 0; p < 16; ++p) {
                    const int r = 4 * p + srow;
                    S[p] = *(const float4*)&sb[r * LSTRIDE + scol * 4];
                }
                float* og = ob + (size_t)(cp - nwarmCh) * CHUNK;
#pragma unroll
                for (int p = 0; p < 16; ++p) {
                    const int r = 4 * p + srow;
                    *(float4*)(og + (size_t)r * L_DIM) = S[p];
                }
            }
            if (c + 1 < nch) {
                const float* g = gb + (c + 1) * CHUNK;
                float* dst = &lds[(c + 1) & 1][0];
#pragma unroll
                for (int p = 0; p < 16; ++p) {
                    const int r = 4 * p + srow;
                    float4 v = *(const float4*)(g + (size_t)r * L_DIM);
                    *(float4*)&dst[r * LSTRIDE + scol * 4] = v;
                }
            }
            __syncthreads();
        }
        // epilogue: store spikes of the final chunk (deposited before the
        // loop's last barrier; only the producer acts past this point)
        {
            const int cp = nch - 1;  // always a main chunk
            float* sb = &lds[cp & 1][0];
            float* og = ob + (size_t)(cp - nwarmCh) * CHUNK;
#pragma unroll
            for (int p = 0; p < 16; ++p) {
                const int r = 4 * p + srow;
                float4 v = *(const float4*)&sb[r * LSTRIDE + scol * 4];
                *(float4*)(og + (size_t)r * L_DIM) = v;
            }
        }
    } else {
        // ---- compute wave (no global memory traffic at all) ----
        const int row = rowBase + lane;
        float u = 0.f, cnt = 0.f, seen = 0.f, accS = 0.f, accF = 0.f;
        bool sp = false;
        const float cdiv = 0.05f;  // RN(1/20)

        __syncthreads();  // chunk 0 staged
        for (int c = 0; c < nch; ++c) {
            float* buf = &lds[c & 1][lane * LSTRIDE];
            float4 R[CF4];
#pragma unroll
            for (int j = 0; j < CF4; ++j) R[j] = *(const float4*)(buf + 4 * j);

            if (c < nwarmCh) {
#pragma unroll
                for (int j = 0; j < CF4; ++j) {
                    float4 iv = R[j];
                    WARM_STEP(iv.x) WARM_STEP(iv.y) WARM_STEP(iv.z) WARM_STEP(iv.w)
                }
            } else {
                // overwrite own input buffer with spikes (reads already in R)
#pragma unroll
                for (int j = 0; j < CF4; ++j) {
                    float4 iv = R[j];
                    float4 sv;
                    FULL_STEP(iv.x, sv.x) FULL_STEP(iv.y, sv.y)
                    FULL_STEP(iv.z, sv.z) FULL_STEP(iv.w, sv.w)
                    *(float4*)(buf + 4 * j) = sv;
                }
            }
            __syncthreads();
        }

        // per-segment partials (all exact integers < 2^24 -> float atomics exact)
        if (cnt > 0.f) {
            const int firstLocal = (int)((float)SEGLEN - accF);
            atomicMin(&firstAcc[row], t0 + firstLocal);
        }
        atomicAdd(&Cacc[row], cnt);
        // sum_t t_global*s = (t0+SEGLEN)*cnt - accS
        atomicAdd(&tsAcc[row], fmaf((float)(t0 + SEGLEN), cnt, -accS));
    }
}

__global__ __launch_bounds__(256) void fin_kernel(const float* __restrict__ Cacc,
                                                  const float* __restrict__ tsAcc,
                                                  const int* __restrict__ firstAcc,
                                                  float* __restrict__ out) {
    int r = blockIdx.x * 256 + threadIdx.x;
    if (r < B_DIM) {
        out[(size_t)B_DIM * L_DIM + r] = (float)firstAcc[r];
        out[(size_t)B_DIM * L_DIM + B_DIM + r] = tsAcc[r] / (Cacc[r] + 1e-6f);
    }
}

extern "C" void kernel_launch(void* const* d_in, const int* in_sizes, int n_in,
                              void* d_out, int out_size, void* d_ws, size_t ws_size,
                              hipStream_t stream) {
    const float* I = (const float*)d_in[0];
    float* out = (float*)d_out;
    float* wsf = (float*)d_ws;
    int* wsi = (int*)((float*)d_ws + 2 * B_DIM);
    (void)in_sizes; (void)n_in; (void)out_size; (void)ws_size;

    init_kernel<<<(2 * B_DIM + 255) / 256, 256, 0, stream>>>(wsf, wsi);
    lif_kernel<<<NSEG * 64, 128, 0, stream>>>(I, out, wsf, wsf + B_DIM, wsi);
    fin_kernel<<<(B_DIM + 255) / 256, 256, 0, stream>>>(wsf, wsf + B_DIM, wsi, out);
}